// Round 22
// baseline (98.297 us; speedup 1.0000x reference)
//
#include <hip/hip_runtime.h>
#include <math.h>

// Problem constants
#define NB 1024
#define NC 5994
#define NCP 6144   // padded row count for wb (96 c-tiles of 64)
#define NCS 6016   // cosb row stride (16B-aligned)
#define NK 512
#define NA 3
#define NT 48      // total K-steps: NA * (NK/32)
#define SCALE_F 30.0f

// Margin constants
#define COS_M_F 0.9800665778412416f
#define SIN_M_F 0.19866933079506122f
#define TH_F (-0.9800665778412416f)
#define MM_F 0.039733866159012244f
#define SUB_COS_M_F 0.9982005399352042f
#define SUB_SIN_M_F (-0.05996400647944459f)
#define SUB_TH_F (-0.9982005399352042f)
#define SUB_MM_F 0.0035978403887666754f

typedef __attribute__((ext_vector_type(8))) short short8;   // 8 bf16 (4 VGPRs)
typedef __attribute__((ext_vector_type(8))) unsigned short ushort8;
typedef __attribute__((ext_vector_type(4))) float f32x4;    // MFMA accumulator

__device__ __forceinline__ float waveReduceSum(float v) {
#pragma unroll
  for (int off = 32; off > 0; off >>= 1) v += __shfl_down(v, off);
  return v;
}

__device__ __forceinline__ void waveArgMax(float& v, int& i) {
#pragma unroll
  for (int off = 32; off > 0; off >>= 1) {
    float ov = __shfl_down(v, off);
    int oi = __shfl_down(i, off);
    if (ov > v || (ov == v && (unsigned)oi < (unsigned)i)) { v = ov; i = oi; }
  }
}

__device__ __forceinline__ ushort f2bf(float f) {
  unsigned u = __float_as_uint(f);
  u += 0x7FFFu + ((u >> 16) & 1u);
  return (ushort)(u >> 16);
}

__device__ __forceinline__ float bf2f(ushort u) {
  return __uint_as_float(((unsigned)u) << 16);
}

// Fused L2-normalize + bf16 convert (R16-proven). 4 rows/block, 1 row/wave.
__global__ __launch_bounds__(256) void norm_convert(const float* __restrict__ x,
                                                    const float* __restrict__ w,
                                                    ushort* __restrict__ xb,
                                                    ushort* __restrict__ wb) {
  const int row = blockIdx.x * 4 + (threadIdx.x >> 6);
  const int lane = threadIdx.x & 63;
  const float* src;
  ushort* dst;
  if (row < NB) {
    src = x + (size_t)row * NK;
    dst = xb + (size_t)row * NK;
  } else {
    const int r = row - NB;           // 0 .. NA*NCP-1
    const int a = r / NCP, c = r % NCP;
    dst = wb + (size_t)r * NK;
    if (c >= NC) {                    // zero-fill padding row
      ushort4 z = {0, 0, 0, 0};
      *(ushort4*)(dst + lane * 4) = z;
      *(ushort4*)(dst + 256 + lane * 4) = z;
      return;
    }
    src = w + ((size_t)a * NC + c) * NK;
  }
  const float4 v0 = *(const float4*)(src + lane * 4);
  const float4 v1 = *(const float4*)(src + 256 + lane * 4);
  float ss = v0.x * v0.x + v0.y * v0.y + v0.z * v0.z + v0.w * v0.w +
             v1.x * v1.x + v1.y * v1.y + v1.z * v1.z + v1.w * v1.w;
  ss = waveReduceSum(ss);
  ss = __shfl(ss, 0);
  const float rn = 1.0f / fmaxf(sqrtf(ss), 1e-12f);
  ushort4 o0 = {f2bf(v0.x * rn), f2bf(v0.y * rn), f2bf(v0.z * rn), f2bf(v0.w * rn)};
  ushort4 o1 = {f2bf(v1.x * rn), f2bf(v1.y * rn), f2bf(v1.z * rn), f2bf(v1.w * rn)};
  *(ushort4*)(dst + lane * 4) = o0;
  *(ushort4*)(dst + 256 + lane * 4) = o1;
}

// cosine[b,c] = max_a dot(xn[b,:], wn[a,c,:])  via bf16 MFMA, fp32 accum.
// LDS-FREE REGISTER GEMM: one wave per block, 64x64 tile, fragments loaded
// DIRECTLY global->VGPR (8x global_load_dwordx4 per K-step, 16B aligned,
// 64B/row segments) with explicit register double-buffering (load t+1,
// MFMA on t). No LDS, no barriers, no global_load_lds: the compiler inserts
// fine-grained vmcnt(N) before first use and pipelines loads across steps
// (G7) — the all-or-nothing drain of the LDS path (R8-R20 plateau) is gone.
// Data is L2-resident: XCD swizzle (id=(cx&7)+8*by+128*(cx>>3), bijective
// on 8*16*12=1536) keeps per-XCD set at B 2.36MB + A 1MB < 4MB L2.
// Grid 1536 = 6 independent wave-chains/CU; VGPR ~205 -> 2 waves/SIMD cap.
__global__ __launch_bounds__(64) void cos_gemm_mfma(const ushort* __restrict__ Xb,
                                                    const ushort* __restrict__ Wb,
                                                    ushort* __restrict__ cosb) {
  const int lane = threadIdx.x;

  const int id = blockIdx.x;
  const int cx = (id & 7) + ((id >> 7) << 3);   // 0..95
  const int by = (id >> 3) & 15;                // 0..15
  const int b0 = by * 64;
  const int c0 = cx * 64;

  // fragment source: lane (r,kg) reads row base+mi*16+r, k-bytes kg*16..+15
  const int r = lane & 15;
  const int kg = lane >> 4;
  const ushort* pA = Xb + (size_t)(b0 + r) * NK + kg * 8;   // + mi*16*NK + k0
  const ushort* pB = Wb + (size_t)(c0 + r) * NK + kg * 8;   // + ni*16*NK + boff

  f32x4 best[4][4];
  f32x4 acc[4][4];
#pragma unroll
  for (int i = 0; i < 4; ++i)
#pragma unroll
    for (int j = 0; j < 4; ++j) {
#pragma unroll
      for (int q = 0; q < 4; ++q) best[i][j][q] = -INFINITY;
      acc[i][j] = (f32x4)(0.f);
    }

  short8 af0[4], bf0[4], af1[4], bf1[4];

#define LOADF(TT, AF, BF)                                                       \
  {                                                                             \
    const int tt_ = (TT);                                                       \
    const int k0 = (tt_ & 15) << 5;                                             \
    const size_t boff = (size_t)(tt_ >> 4) * NCP * NK + k0;                     \
    _Pragma("unroll") for (int mi = 0; mi < 4; ++mi)                            \
        AF[mi] = *(const short8*)(pA + (size_t)mi * 16 * NK + k0);              \
    _Pragma("unroll") for (int ni = 0; ni < 4; ++ni)                            \
        BF[ni] = *(const short8*)(pB + (size_t)ni * 16 * NK + boff);            \
  }

#define MFMA16(AF, BF, T)                                                       \
  {                                                                             \
    _Pragma("unroll") for (int mi = 0; mi < 4; ++mi)                            \
        _Pragma("unroll") for (int ni = 0; ni < 4; ++ni)                        \
            acc[mi][ni] = __builtin_amdgcn_mfma_f32_16x16x32_bf16(              \
                AF[mi], BF[ni], acc[mi][ni], 0, 0, 0);                          \
    if (((T) & 15) == 15) {                                                     \
      _Pragma("unroll") for (int i = 0; i < 4; ++i)                             \
          _Pragma("unroll") for (int j = 0; j < 4; ++j) {                       \
        _Pragma("unroll") for (int q = 0; q < 4; ++q)                           \
            best[i][j][q] = fmaxf(best[i][j][q], acc[i][j][q]);                 \
        acc[i][j] = (f32x4)(0.f);                                               \
      }                                                                         \
    }                                                                           \
  }

  // prologue: fragments for t=0
  LOADF(0, af0, bf0)
#pragma unroll
  for (int t = 0; t < NT; t += 2) {
    if (t + 1 < NT) LOADF(t + 1, af1, bf1)   // issue next loads first
    MFMA16(af0, bf0, t)                      // compute current (covers latency)
    if (t + 2 < NT) LOADF(t + 2, af0, bf0)
    MFMA16(af1, bf1, t + 1)
  }
#undef LOADF
#undef MFMA16

  // C/D layout: col = lane&15, row = (lane>>4)*4 + q   [measured m89/m91]
  const int q4 = kg * 4;
#pragma unroll
  for (int ni = 0; ni < 4; ++ni) {
    const int col = c0 + ni * 16 + r;
    if (col < NC) {
#pragma unroll
      for (int mi = 0; mi < 4; ++mi) {
        const int row0 = b0 + mi * 16 + q4;
#pragma unroll
        for (int q = 0; q < 4; ++q)
          cosb[(size_t)(row0 + q) * NCS + col] = f2bf(best[mi][ni][q]);
      }
    }
  }
}

// Per-row loss (R16-proven): 256 threads/row, ushort8 loads (16B/lane),
// register-resident 24 elems/thread; idx = j*2048 + tid*8 + e.
__global__ __launch_bounds__(256) void row_loss(const ushort* __restrict__ cosb,
                                                const int* __restrict__ label,
                                                float* __restrict__ loss_b,
                                                float* __restrict__ corr_b) {
  __shared__ float swv[4];
  __shared__ int swi[4];
  __shared__ float s_red[4];
  __shared__ float s_maxv;
  __shared__ float s_cosL;
  __shared__ float topv[6];
  __shared__ int topi[6];

  const int b = blockIdx.x, tid = threadIdx.x;
  const int wv = tid >> 6;
  const int lab = label[b];
  const ushort* row = cosb + (size_t)b * NCS;

  float v[24];
  float bv = -INFINITY;
  int bi = -1;
#pragma unroll
  for (int j = 0; j < 3; ++j) {
    const ushort8 u = *(const ushort8*)(row + j * 2048 + tid * 8);
#pragma unroll
    for (int e = 0; e < 8; ++e) {
      const int idx = j * 2048 + tid * 8 + e;
      const float f = (idx < NC) ? bf2f(u[e]) : -INFINITY;
      v[j * 8 + e] = f;
      if (f > bv) { bv = f; bi = idx; }   // ascending idx scan -> first occurrence
      if (idx == lab) s_cosL = f;
    }
  }
  waveArgMax(bv, bi);
  if ((tid & 63) == 0) { swv[wv] = bv; swi[wv] = bi; }
  __syncthreads();
  if (tid == 0) {
    float mv = swv[0]; int mi = swi[0];
    for (int q = 1; q < 4; ++q)
      if (swv[q] > mv || (swv[q] == mv && (unsigned)swi[q] < (unsigned)mi)) { mv = swv[q]; mi = swi[q]; }
    s_maxv = mv; topv[0] = mv; topi[0] = mi;
  }
  __syncthreads();
  const float maxv = s_maxv;

  float ps = 0.f;
#pragma unroll
  for (int j = 0; j < 24; ++j) ps += __expf(SCALE_F * (v[j] - maxv));
  ps = waveReduceSum(ps);
  if ((tid & 63) == 0) s_red[wv] = ps;

  // exclusion bitmap: element idx -> owner tid = (idx&2047)>>3,
  // slot = ((idx>>11)<<3) | (idx&7)
  unsigned excl = 0;
  {
    const int wi = topi[0];
    if (((wi & 2047) >> 3) == tid) excl |= 1u << (((wi >> 11) << 3) | (wi & 7));
  }

  for (int e = 1; e < 6; ++e) {
    float lv = -INFINITY;
    int li = -1;
#pragma unroll
    for (int j = 0; j < 3; ++j)
#pragma unroll
      for (int k = 0; k < 8; ++k) {
        const int s = j * 8 + k;
        if (!((excl >> s) & 1u) && v[s] > lv) { lv = v[s]; li = j * 2048 + tid * 8 + k; }
      }
    waveArgMax(lv, li);
    if ((tid & 63) == 0) { swv[wv] = lv; swi[wv] = li; }
    __syncthreads();
    if (tid == 0) {
      float mv = swv[0]; int mi = swi[0];
      for (int q = 1; q < 4; ++q)
        if (swv[q] > mv || (swv[q] == mv && (unsigned)swi[q] < (unsigned)mi)) { mv = swv[q]; mi = swi[q]; }
      topv[e] = mv; topi[e] = mi;
    }
    __syncthreads();
    const int wi = topi[e];
    if (((wi & 2047) >> 3) == tid) excl |= 1u << (((wi >> 11) << 3) | (wi & 7));
  }

  if (tid == 0) {
    const float S = s_red[0] + s_red[1] + s_red[2] + s_red[3];
    const float m = SCALE_F * maxv;
    const float cosL = s_cosL;
    const float sineL = sqrtf(fminf(fmaxf(1.f - cosL * cosL, 0.f), 1.f));
    const float phiL = (cosL - TH_F > 0.f) ? (cosL * COS_M_F - sineL * SIN_M_F) : (cosL - MM_F);
    float adj = __expf(SCALE_F * phiL - m) - __expf(SCALE_F * cosL - m);
    int cnt = 0;
    for (int e = 0; e < 6 && cnt < 5; ++e) {
      if (topi[e] == lab) continue;
      const float c = topv[e];
      const float sine = sqrtf(fminf(fmaxf(1.f - c * c, 0.f), 1.f));
      const float sp = (c - SUB_TH_F > 0.f) ? (c * SUB_COS_M_F - sine * SUB_SIN_M_F) : (c - SUB_MM_F);
      adj += __expf(SCALE_F * sp - m) - __expf(SCALE_F * c - m);
      ++cnt;
    }
    const float Sp = S + adj;
    loss_b[b] = (logf(Sp) + m) - SCALE_F * phiL;
    corr_b[b] = (topi[0] == lab) ? 1.f : 0.f;
  }
}

__global__ __launch_bounds__(256) void finalize(const float* __restrict__ loss_b,
                                                const float* __restrict__ corr_b,
                                                float* __restrict__ out) {
  const int tid = threadIdx.x;
  float ls = 0.f, cs = 0.f;
  for (int i = tid; i < NB; i += 256) { ls += loss_b[i]; cs += corr_b[i]; }
  ls = waveReduceSum(ls);
  cs = waveReduceSum(cs);
  __shared__ float sl[4], sc[4];
  if ((tid & 63) == 0) { sl[tid >> 6] = ls; sc[tid >> 6] = cs; }
  __syncthreads();
  if (tid == 0) {
    const float L = sl[0] + sl[1] + sl[2] + sl[3];
    const float Cr = sc[0] + sc[1] + sc[2] + sc[3];
    out[0] = L / (float)NB;
    out[1] = Cr / (float)NB * 100.f;
  }
}

extern "C" void kernel_launch(void* const* d_in, const int* in_sizes, int n_in,
                              void* d_out, int out_size, void* d_ws, size_t ws_size,
                              hipStream_t stream) {
  const float* x = (const float*)d_in[0];      // [1024, 512]
  const float* w = (const float*)d_in[1];      // [3, 5994, 512]
  const int* label = (const int*)d_in[2];      // [1024]
  float* out = (float*)d_out;                  // [2] = {loss, prec1}
  char* ws = (char*)d_ws;

  // workspace layout (bytes) — total 32.2 MB, within proven footprint:
  ushort* xb = (ushort*)ws;                                    // 1,048,576
  ushort* wb = (ushort*)(ws + 1048576);                        // 18,874,368
  ushort* cosb = (ushort*)(ws + 1048576 + 18874368);           // 12,320,768 (bf16, stride 6016)
  float* loss_b = (float*)ws;                                  // reuses dead xb
  float* corr_b = (float*)(ws + 4096);

  norm_convert<<<(NB + NA * NCP) / 4, 256, 0, stream>>>(x, w, xb, wb);
  cos_gemm_mfma<<<16 * 96, 64, 0, stream>>>(xb, wb, cosb);
  row_loss<<<NB, 256, 0, stream>>>(cosb, label, loss_b, corr_b);
  finalize<<<1, 256, 0, stream>>>(loss_b, corr_b, out);
}

// Round 23
// 65.583 us; speedup vs baseline: 1.4988x; 1.4988x over previous
//
#include <hip/hip_runtime.h>
#include <math.h>

// Problem constants
#define NB 1024
#define NC 5994
#define NCP 6144   // padded row count for wb (48 c-tiles of 128)
#define NCS 6016   // cosb row stride (16B-aligned)
#define NK 512
#define NA 3
#define NT 48      // total K-steps: NA * (NK/32)
#define SCALE_F 30.0f

// Margin constants
#define COS_M_F 0.9800665778412416f
#define SIN_M_F 0.19866933079506122f
#define TH_F (-0.9800665778412416f)
#define MM_F 0.039733866159012244f
#define SUB_COS_M_F 0.9982005399352042f
#define SUB_SIN_M_F (-0.05996400647944459f)
#define SUB_TH_F (-0.9982005399352042f)
#define SUB_MM_F 0.0035978403887666754f

typedef __attribute__((ext_vector_type(8))) short short8;   // 8 bf16 (4 VGPRs)
typedef __attribute__((ext_vector_type(8))) unsigned short ushort8;
typedef __attribute__((ext_vector_type(4))) float f32x4;    // MFMA accumulator

__device__ __forceinline__ float waveReduceSum(float v) {
#pragma unroll
  for (int off = 32; off > 0; off >>= 1) v += __shfl_down(v, off);
  return v;
}

__device__ __forceinline__ void waveArgMax(float& v, int& i) {
#pragma unroll
  for (int off = 32; off > 0; off >>= 1) {
    float ov = __shfl_down(v, off);
    int oi = __shfl_down(i, off);
    if (ov > v || (ov == v && (unsigned)oi < (unsigned)i)) { v = ov; i = oi; }
  }
}

__device__ __forceinline__ ushort f2bf(float f) {
  unsigned u = __float_as_uint(f);
  u += 0x7FFFu + ((u >> 16) & 1u);
  return (ushort)(u >> 16);
}

__device__ __forceinline__ float bf2f(ushort u) {
  return __uint_as_float(((unsigned)u) << 16);
}

__device__ __forceinline__ void load_lds16(const ushort* g, ushort* l) {
  __builtin_amdgcn_global_load_lds(
      (const __attribute__((address_space(1))) unsigned int*)g,
      (__attribute__((address_space(3))) unsigned int*)l, 16, 0, 0);
}

// Fused L2-normalize + bf16 convert (R16-proven). 4 rows/block, 1 row/wave.
__global__ __launch_bounds__(256) void norm_convert(const float* __restrict__ x,
                                                    const float* __restrict__ w,
                                                    ushort* __restrict__ xb,
                                                    ushort* __restrict__ wb) {
  const int row = blockIdx.x * 4 + (threadIdx.x >> 6);
  const int lane = threadIdx.x & 63;
  const float* src;
  ushort* dst;
  if (row < NB) {
    src = x + (size_t)row * NK;
    dst = xb + (size_t)row * NK;
  } else {
    const int r = row - NB;           // 0 .. NA*NCP-1
    const int a = r / NCP, c = r % NCP;
    dst = wb + (size_t)r * NK;
    if (c >= NC) {                    // zero-fill padding row
      ushort4 z = {0, 0, 0, 0};
      *(ushort4*)(dst + lane * 4) = z;
      *(ushort4*)(dst + 256 + lane * 4) = z;
      return;
    }
    src = w + ((size_t)a * NC + c) * NK;
  }
  const float4 v0 = *(const float4*)(src + lane * 4);
  const float4 v1 = *(const float4*)(src + 256 + lane * 4);
  float ss = v0.x * v0.x + v0.y * v0.y + v0.z * v0.z + v0.w * v0.w +
             v1.x * v1.x + v1.y * v1.y + v1.z * v1.z + v1.w * v1.w;
  ss = waveReduceSum(ss);
  ss = __shfl(ss, 0);
  const float rn = 1.0f / fmaxf(sqrtf(ss), 1e-12f);
  ushort4 o0 = {f2bf(v0.x * rn), f2bf(v0.y * rn), f2bf(v0.z * rn), f2bf(v0.w * rn)};
  ushort4 o1 = {f2bf(v1.x * rn), f2bf(v1.y * rn), f2bf(v1.z * rn), f2bf(v1.w * rn)};
  *(ushort4*)(dst + lane * 4) = o0;
  *(ushort4*)(dst + 256 + lane * 4) = o1;
}

// cosine[b,c] = max_a dot(xn[b,:], wn[a,c,:])  via bf16 MFMA, fp32 accum.
// LOCKED R8/R13/R16 kernel — measured optimum over 13 structural/addressing
// probes (R9-R22): 64x128 tile, 2 waves, double-buffer, ONE __syncthreads
// per K-step, slot-rotation swizzle (VMEM quad-coalesced + conflict-free
// ds_read), XCD swizzle, grid 768 = 3 blocks/CU, 24KB LDS, bf16 epilogue
// @ stride NCS.
__global__ __launch_bounds__(128) void cos_gemm_mfma(const ushort* __restrict__ Xb,
                                                     const ushort* __restrict__ Wb,
                                                     ushort* __restrict__ cosb) {
  __shared__ ushort sA0[64 * 32];   // 4 KB each
  __shared__ ushort sA1[64 * 32];
  __shared__ ushort sB0[128 * 32];  // 8 KB each
  __shared__ ushort sB1[128 * 32];
  const int tid = threadIdx.x;
  const int lane = tid & 63;
  const int w = tid >> 6;           // 0..1

  // swizzle: id = (cx&7) + 8*by + 128*(cx>>3)  (bijective on 8*16*6 = 768)
  const int id = blockIdx.x;
  const int cx = (id & 7) + ((id >> 7) << 3);   // 0..47
  const int by = (id >> 3) & 15;                // 0..15
  const int b0 = by * 64;
  const int c0 = cx * 128;

  // staging source: quad-contiguous rows, chunk rotated (R8-proven):
  const int lrow = lane >> 2;
  const int skg = ((lane & 3) - ((lane >> 3) & 3)) & 3;
  const ushort* gA = Xb + (size_t)(b0 + w * 32 + lrow) * NK + skg * 8;
  const ushort* gB = Wb + (size_t)(c0 + w * 64 + lrow) * NK + skg * 8;
  const int ldsA = w * 1024;        // A sub-blocks {2w,2w+1}
  const int ldsB = w * 2048;        // B sub-blocks {4w..4w+3}
  const int w4 = w * 4;

  // fragment-read offset: r*32 + (((kg + (r>>1)) & 3) * 8)  (R8-proven)
  const int r = lane & 15;
  const int kg = lane >> 4;
  const int rdoff = r * 32 + (((kg + (r >> 1)) & 3) * 8);

  f32x4 best[4][4];
  f32x4 acc[4][4];
#pragma unroll
  for (int i = 0; i < 4; ++i)
#pragma unroll
    for (int j = 0; j < 4; ++j) {
#pragma unroll
      for (int q = 0; q < 4; ++q) best[i][j][q] = -INFINITY;
      acc[i][j] = (f32x4)(0.f);
    }

  // prologue: stage t=0 into buffer 0
  load_lds16(gA, (ushort*)sA0 + ldsA);
  load_lds16(gA + 16 * NK, (ushort*)sA0 + ldsA + 512);
#pragma unroll
  for (int j = 0; j < 4; ++j)
    load_lds16(gB + (size_t)j * 16 * NK, (ushort*)sB0 + ldsB + j * 512);
  __syncthreads();

#define GEMM_BODY(T, SAr, SBr, SAw, SBw)                                        \
  {                                                                             \
    const int t_ = (T);                                                         \
    if (t_ + 1 < NT) {                                                          \
      const int tn = t_ + 1;                                                    \
      const int k0 = (tn & 15) << 5;                                            \
      const size_t boff = (size_t)(tn >> 4) * NCP * NK + k0;                    \
      load_lds16(gA + k0, (ushort*)SAw + ldsA);                                 \
      load_lds16(gA + k0 + 16 * NK, (ushort*)SAw + ldsA + 512);                 \
      _Pragma("unroll") for (int j = 0; j < 4; ++j)                             \
          load_lds16(gB + boff + (size_t)j * 16 * NK,                           \
                     (ushort*)SBw + ldsB + j * 512);                            \
    }                                                                           \
    short8 af[4], bf[4];                                                        \
    _Pragma("unroll") for (int mi = 0; mi < 4; ++mi)                            \
        af[mi] = *(const short8*)&SAr[mi * 512 + rdoff];                        \
    _Pragma("unroll") for (int ni = 0; ni < 4; ++ni)                            \
        bf[ni] = *(const short8*)&SBr[(w4 + ni) * 512 + rdoff];                 \
    _Pragma("unroll") for (int mi = 0; mi < 4; ++mi)                            \
        _Pragma("unroll") for (int ni = 0; ni < 4; ++ni)                        \
            acc[mi][ni] = __builtin_amdgcn_mfma_f32_16x16x32_bf16(              \
                af[mi], bf[ni], acc[mi][ni], 0, 0, 0);                          \
    if ((t_ & 15) == 15) {                                                      \
      _Pragma("unroll") for (int i = 0; i < 4; ++i)                             \
          _Pragma("unroll") for (int j = 0; j < 4; ++j) {                       \
        _Pragma("unroll") for (int q = 0; q < 4; ++q)                           \
            best[i][j][q] = fmaxf(best[i][j][q], acc[i][j][q]);                 \
        acc[i][j] = (f32x4)(0.f);                                               \
      }                                                                         \
    }                                                                           \
    __syncthreads();                                                            \
  }

  for (int t = 0; t < NT; t += 2) {
    GEMM_BODY(t, sA0, sB0, sA1, sB1)
    GEMM_BODY(t + 1, sA1, sB1, sA0, sB0)
  }
#undef GEMM_BODY

  // C/D layout: col = lane&15, row = (lane>>4)*4 + q   [measured m89/m91]
  const int q4 = (lane >> 4) * 4;
#pragma unroll
  for (int ni = 0; ni < 4; ++ni) {
    const int col = c0 + w * 64 + ni * 16 + r;
    if (col < NC) {
#pragma unroll
      for (int mi = 0; mi < 4; ++mi) {
        const int row0 = b0 + mi * 16 + q4;
#pragma unroll
        for (int q = 0; q < 4; ++q)
          cosb[(size_t)(row0 + q) * NCS + col] = f2bf(best[mi][ni][q]);
      }
    }
  }
}

// Per-row loss (R16-proven): 256 threads/row, ushort8 loads (16B/lane),
// register-resident 24 elems/thread; idx = j*2048 + tid*8 + e
// (index-ascending per thread -> first-occurrence argmax = stable top_k).
__global__ __launch_bounds__(256) void row_loss(const ushort* __restrict__ cosb,
                                                const int* __restrict__ label,
                                                float* __restrict__ loss_b,
                                                float* __restrict__ corr_b) {
  __shared__ float swv[4];
  __shared__ int swi[4];
  __shared__ float s_red[4];
  __shared__ float s_maxv;
  __shared__ float s_cosL;
  __shared__ float topv[6];
  __shared__ int topi[6];

  const int b = blockIdx.x, tid = threadIdx.x;
  const int wv = tid >> 6;
  const int lab = label[b];
  const ushort* row = cosb + (size_t)b * NCS;

  float v[24];
  float bv = -INFINITY;
  int bi = -1;
#pragma unroll
  for (int j = 0; j < 3; ++j) {
    const ushort8 u = *(const ushort8*)(row + j * 2048 + tid * 8);
#pragma unroll
    for (int e = 0; e < 8; ++e) {
      const int idx = j * 2048 + tid * 8 + e;
      const float f = (idx < NC) ? bf2f(u[e]) : -INFINITY;
      v[j * 8 + e] = f;
      if (f > bv) { bv = f; bi = idx; }   // ascending idx scan -> first occurrence
      if (idx == lab) s_cosL = f;
    }
  }
  waveArgMax(bv, bi);
  if ((tid & 63) == 0) { swv[wv] = bv; swi[wv] = bi; }
  __syncthreads();
  if (tid == 0) {
    float mv = swv[0]; int mi = swi[0];
    for (int q = 1; q < 4; ++q)
      if (swv[q] > mv || (swv[q] == mv && (unsigned)swi[q] < (unsigned)mi)) { mv = swv[q]; mi = swi[q]; }
    s_maxv = mv; topv[0] = mv; topi[0] = mi;
  }
  __syncthreads();
  const float maxv = s_maxv;

  float ps = 0.f;
#pragma unroll
  for (int j = 0; j < 24; ++j) ps += __expf(SCALE_F * (v[j] - maxv));
  ps = waveReduceSum(ps);
  if ((tid & 63) == 0) s_red[wv] = ps;

  // exclusion bitmap: element idx -> owner tid = (idx&2047)>>3,
  // slot = ((idx>>11)<<3) | (idx&7)
  unsigned excl = 0;
  {
    const int wi = topi[0];
    if (((wi & 2047) >> 3) == tid) excl |= 1u << (((wi >> 11) << 3) | (wi & 7));
  }

  for (int e = 1; e < 6; ++e) {
    float lv = -INFINITY;
    int li = -1;
#pragma unroll
    for (int j = 0; j < 3; ++j)
#pragma unroll
      for (int k = 0; k < 8; ++k) {
        const int s = j * 8 + k;
        if (!((excl >> s) & 1u) && v[s] > lv) { lv = v[s]; li = j * 2048 + tid * 8 + k; }
      }
    waveArgMax(lv, li);
    if ((tid & 63) == 0) { swv[wv] = lv; swi[wv] = li; }
    __syncthreads();
    if (tid == 0) {
      float mv = swv[0]; int mi = swi[0];
      for (int q = 1; q < 4; ++q)
        if (swv[q] > mv || (swv[q] == mv && (unsigned)swi[q] < (unsigned)mi)) { mv = swv[q]; mi = swi[q]; }
      topv[e] = mv; topi[e] = mi;
    }
    __syncthreads();
    const int wi = topi[e];
    if (((wi & 2047) >> 3) == tid) excl |= 1u << (((wi >> 11) << 3) | (wi & 7));
  }

  if (tid == 0) {
    const float S = s_red[0] + s_red[1] + s_red[2] + s_red[3];
    const float m = SCALE_F * maxv;
    const float cosL = s_cosL;
    const float sineL = sqrtf(fminf(fmaxf(1.f - cosL * cosL, 0.f), 1.f));
    const float phiL = (cosL - TH_F > 0.f) ? (cosL * COS_M_F - sineL * SIN_M_F) : (cosL - MM_F);
    float adj = __expf(SCALE_F * phiL - m) - __expf(SCALE_F * cosL - m);
    int cnt = 0;
    for (int e = 0; e < 6 && cnt < 5; ++e) {
      if (topi[e] == lab) continue;
      const float c = topv[e];
      const float sine = sqrtf(fminf(fmaxf(1.f - c * c, 0.f), 1.f));
      const float sp = (c - SUB_TH_F > 0.f) ? (c * SUB_COS_M_F - sine * SUB_SIN_M_F) : (c - SUB_MM_F);
      adj += __expf(SCALE_F * sp - m) - __expf(SCALE_F * c - m);
      ++cnt;
    }
    const float Sp = S + adj;
    loss_b[b] = (logf(Sp) + m) - SCALE_F * phiL;
    corr_b[b] = (topi[0] == lab) ? 1.f : 0.f;
  }
}

__global__ __launch_bounds__(256) void finalize(const float* __restrict__ loss_b,
                                                const float* __restrict__ corr_b,
                                                float* __restrict__ out) {
  const int tid = threadIdx.x;
  float ls = 0.f, cs = 0.f;
  for (int i = tid; i < NB; i += 256) { ls += loss_b[i]; cs += corr_b[i]; }
  ls = waveReduceSum(ls);
  cs = waveReduceSum(cs);
  __shared__ float sl[4], sc[4];
  if ((tid & 63) == 0) { sl[tid >> 6] = ls; sc[tid >> 6] = cs; }
  __syncthreads();
  if (tid == 0) {
    const float L = sl[0] + sl[1] + sl[2] + sl[3];
    const float Cr = sc[0] + sc[1] + sc[2] + sc[3];
    out[0] = L / (float)NB;
    out[1] = Cr / (float)NB * 100.f;
  }
}

extern "C" void kernel_launch(void* const* d_in, const int* in_sizes, int n_in,
                              void* d_out, int out_size, void* d_ws, size_t ws_size,
                              hipStream_t stream) {
  const float* x = (const float*)d_in[0];      // [1024, 512]
  const float* w = (const float*)d_in[1];      // [3, 5994, 512]
  const int* label = (const int*)d_in[2];      // [1024]
  float* out = (float*)d_out;                  // [2] = {loss, prec1}
  char* ws = (char*)d_ws;

  // workspace layout (bytes) — total 32.2 MB, within proven footprint:
  ushort* xb = (ushort*)ws;                                    // 1,048,576
  ushort* wb = (ushort*)(ws + 1048576);                        // 18,874,368
  ushort* cosb = (ushort*)(ws + 1048576 + 18874368);           // 12,320,768 (bf16, stride 6016)
  float* loss_b = (float*)ws;                                  // reuses dead xb
  float* corr_b = (float*)(ws + 4096);

  norm_convert<<<(NB + NA * NCP) / 4, 256, 0, stream>>>(x, w, xb, wb);
  cos_gemm_mfma<<<16 * 48, 128, 0, stream>>>(xb, wb, cosb);
  row_loss<<<NB, 256, 0, stream>>>(cosb, label, loss_b, corr_b);
  finalize<<<1, 256, 0, stream>>>(loss_b, corr_b, out);
}